// Round 17
// baseline (1647.770 us; speedup 1.0000x reference)
//
#include <hip/hip_runtime.h>
#include <hip/hip_cooperative_groups.h>
#include <hip/hip_bf16.h>

namespace cg = cooperative_groups;

#define N_NODES  10000
#define N_EDGES  64000
#define N_GRAPHS 64
#define HID      64

typedef __attribute__((ext_vector_type(8))) short short8;
typedef __attribute__((ext_vector_type(4))) float f32x4;
typedef __attribute__((ext_vector_type(2))) float f32x2;

__device__ __forceinline__ float lrelu(float v){ return v > 0.f ? v : 0.01f*v; }

__device__ __forceinline__ unsigned short f2bf(float f){
    union { float f; unsigned u; } v; v.f = f;
    unsigned r = v.u + 0x7fff + ((v.u >> 16) & 1);
    return (unsigned short)(r >> 16);
}
__device__ __forceinline__ float bf2f(unsigned short s){
    union { unsigned u; float f; } v; v.u = ((unsigned)s) << 16;
    return v.f;
}
__device__ __forceinline__ short8 pack_bf8(float4 a, float4 b){
    short8 r;
    r[0]=(short)f2bf(a.x); r[1]=(short)f2bf(a.y); r[2]=(short)f2bf(a.z); r[3]=(short)f2bf(a.w);
    r[4]=(short)f2bf(b.x); r[5]=(short)f2bf(b.y); r[6]=(short)f2bf(b.z); r[7]=(short)f2bf(b.w);
    return r;
}

// ---------------- shared-memory union (32 KB) ----------------
struct MsgSm {
    unsigned char gl[4096] __attribute__((aligned(16)));
    unsigned short ts[64] __attribute__((aligned(16)));
};
union SMu {
    float tile[64][65];        // pre w2conv
    unsigned stgu[8192];       // gmat staging (32 KB)
    float otile[64][65];       // combine2
    int part[256];             // scan
    MsgSm mw[4];               // msg, per wave
};

// ---------------- all pointers in one param struct ----------------
struct P {
    const float* x; const int* src; const int* dst; const float* ea; const int* batch;
    const float* nfc_w; const float* nfc_b;
    const float* e1w1; const float* e1b1; const float* e1w2; const float* e1b2;
    const float* g1root; const float* g1bias;
    const float* e2w1; const float* e2b1; const float* e2w2; const float* e2b2;
    const float* g2root; const float* g2bias;
    const float* fc1w; const float* fc1b; const float* fc2w; const float* fc2b;
    float* out;
    float *hx1, *hx2, *hb2, *agg, *hg;
    unsigned short *tp1, *tp2, *w2t1, *w2t2, *nfc_wt, *w1t1, *w1t2, *b2t1, *b2t2, *rootT1, *rootT2;
    int *counts, *cursor, *rowptr, *eidx, *dsts;
    unsigned char* G;
};

// ================= stage bodies (shared by mega + fallback kernels) =================

__device__ __forceinline__ void init_body(const P& p, int vb, int tid){
    if (vb < 40){
        int i = vb * 256 + tid;
        if (i < N_NODES) p.counts[i] = 0;
        if (vb < 16) p.hg[vb * 256 + tid] = 0.f;
    } else if (vb == 40){
        for (int idx = tid; idx < 8192; idx += 256){
            int o = idx >> 7, i = idx & 127;
            p.nfc_wt[idx] = f2bf(p.nfc_w[i * 64 + o]);
        }
    } else if (vb <= 42){
        const float* w1 = (vb == 42) ? p.e2w1 : p.e1w1;
        unsigned short* w1t = (vb == 42) ? p.w1t2 : p.w1t1;
        for (int idx = tid; idx < 2048; idx += 256){
            int o = idx >> 5, k = idx & 31;
            w1t[idx] = f2bf(w1[k * 64 + o]);
        }
    } else if (vb <= 44){
        const float* b2 = (vb == 44) ? p.e2b2 : p.e1b2;
        unsigned short* b2t = (vb == 44) ? p.b2t2 : p.b2t1;
        for (int idx = tid; idx < 4096; idx += 256){
            int o = idx >> 6, i = idx & 63;
            b2t[idx] = f2bf(b2[i * 64 + o]);
        }
    } else {
        const float* rt = (vb == 46) ? p.g2root : p.g1root;
        unsigned short* rT = (vb == 46) ? p.rootT2 : p.rootT1;
        for (int idx = tid; idx < 4096; idx += 256){
            int o = idx >> 6, i = idx & 63;
            rT[idx] = f2bf(rt[i * 64 + o]);
        }
    }
}

#define PRE_NFC 157
#define PRE_TG  1000
#define PRE_W2C 128
#define PRE_CNT 250
#define PRE_NVB (PRE_NFC + PRE_TG + PRE_W2C + PRE_CNT)

__device__ __forceinline__ void pre_body(const P& p, SMu& sm, int vb, int tid){
    int wid = tid >> 6, l = tid & 63;
    int m16 = l & 15, grp = l >> 4;
    if (vb < PRE_NFC){
        int node = vb * 64 + wid * 16 + m16;
        bool ok = node < N_NODES;
        short8 xb[4];
        #pragma unroll
        for (int kq = 0; kq < 4; ++kq){
            if (ok){
                const float* xp = p.x + (size_t)node * 128 + kq * 32 + grp * 8;
                xb[kq] = pack_bf8(*(const float4*)xp, *(const float4*)(xp + 4));
            } else {
                short8 z = {0,0,0,0,0,0,0,0}; xb[kq] = z;
            }
        }
        #pragma unroll
        for (int TB = 0; TB < 64; TB += 16){
            f32x4 acc = *(const f32x4*)(p.nfc_b + TB + grp * 4);
            #pragma unroll
            for (int kq = 0; kq < 4; ++kq){
                short8 af = *(const short8*)(p.nfc_wt + (TB + m16) * 128 + kq * 32 + grp * 8);
                acc = __builtin_amdgcn_mfma_f32_16x16x32_bf16(af, xb[kq], acc, 0, 0, 0);
            }
            f32x4 r;
            r[0] = lrelu(acc[0]); r[1] = lrelu(acc[1]); r[2] = lrelu(acc[2]); r[3] = lrelu(acc[3]);
            if (ok) *(f32x4*)(p.hx1 + ((size_t)node << 6) + TB + grp * 4) = r;
        }
    } else if (vb < PRE_NFC + PRE_TG){
        int j = (vb - PRE_NFC) * 64 + wid * 16 + m16;
        const float* row = p.ea + (size_t)j * 32 + grp * 8;
        short8 ef = pack_bf8(*(const float4*)row, *(const float4*)(row + 4));
        #pragma unroll
        for (int TB = 0; TB < 64; TB += 16){
            short8 wf1 = *(const short8*)(p.w1t1 + (TB + m16) * 32 + grp * 8);
            f32x4 a1 = *(const f32x4*)(p.e1b1 + TB + grp * 4);
            a1 = __builtin_amdgcn_mfma_f32_16x16x32_bf16(wf1, ef, a1, 0, 0, 0);
            uint2 q;
            q.x = (unsigned)f2bf(fmaxf(a1[0], 0.f)) | ((unsigned)f2bf(fmaxf(a1[1], 0.f)) << 16);
            q.y = (unsigned)f2bf(fmaxf(a1[2], 0.f)) | ((unsigned)f2bf(fmaxf(a1[3], 0.f)) << 16);
            *(uint2*)(p.tp1 + ((size_t)j << 6) + TB + grp * 4) = q;
            short8 wf2 = *(const short8*)(p.w1t2 + (TB + m16) * 32 + grp * 8);
            f32x4 a2 = *(const f32x4*)(p.e2b1 + TB + grp * 4);
            a2 = __builtin_amdgcn_mfma_f32_16x16x32_bf16(wf2, ef, a2, 0, 0, 0);
            q.x = (unsigned)f2bf(fmaxf(a2[0], 0.f)) | ((unsigned)f2bf(fmaxf(a2[1], 0.f)) << 16);
            q.y = (unsigned)f2bf(fmaxf(a2[2], 0.f)) | ((unsigned)f2bf(fmaxf(a2[3], 0.f)) << 16);
            *(uint2*)(p.tp2 + ((size_t)j << 6) + TB + grp * 4) = q;
        }
    } else if (vb < PRE_NFC + PRE_TG + PRE_W2C){
        int bb = vb - PRE_NFC - PRE_TG;
        int k = bb & 63;
        const float* srcw = ((bb < 64) ? p.e1w2 : p.e2w2) + (size_t)k * 4096;
        unsigned short* dstw = (bb < 64) ? p.w2t1 : p.w2t2;
        for (int idx = tid; idx < 4096; idx += 256) sm.tile[idx >> 6][idx & 63] = srcw[idx];
        __syncthreads();
        for (int idx = tid; idx < 4096; idx += 256){
            int o = idx >> 6, i = idx & 63;
            dstw[((size_t)(k * 64 + o) << 6) + i] = f2bf(sm.tile[i][o]);
        }
        __syncthreads();
    } else {
        int e = (vb - PRE_NFC - PRE_TG - PRE_W2C) * 256 + tid;
        if (e < N_EDGES) atomicAdd(&p.counts[p.src[e]], 1);
    }
}

__device__ __forceinline__ void scan_body(const P& p, SMu& sm, int tid){
    const int CH = 40;
    int base = tid * CH, s = 0;
    int cnt[CH];
    #pragma unroll
    for (int i = 0; i < CH; ++i){
        int idx = base + i;
        int c = (idx < N_NODES) ? p.counts[idx] : 0;
        cnt[i] = c; s += c;
        if (idx < N_NODES) p.cursor[idx] = 0;
    }
    sm.part[tid] = s; __syncthreads();
    for (int off = 1; off < 256; off <<= 1){
        int v = (tid >= off) ? sm.part[tid - off] : 0;
        __syncthreads();
        sm.part[tid] += v;
        __syncthreads();
    }
    int run = sm.part[tid] - s;
    #pragma unroll
    for (int i = 0; i < CH; ++i){
        int idx = base + i;
        if (idx < N_NODES){ p.rowptr[idx] = run; run += cnt[i]; }
    }
    if (tid == 255) p.rowptr[N_NODES] = run;
}

__device__ __forceinline__ void scatter_body(const P& p, int vb, int tid){
    int e = vb * 256 + tid;
    if (e < N_EDGES){
        int s = p.src[e];
        int j = p.rowptr[s] + atomicAdd(&p.cursor[s], 1);
        p.eidx[j] = e; p.dsts[j] = p.dst[e];
    }
}

#define NBH2 157
#define NBG  (157 * 8)
#define LA_NVB (NBH2 + NBG)

__device__ __forceinline__ void layerA_body(const P& p, SMu& sm, int vb, int tid,
        const float* hx, const unsigned short* b2t, const unsigned short* w2t){
    int wid = tid >> 6, l = tid & 63;
    int m16 = l & 15, grp = l >> 4;
    if (vb < NBH2){
        int node = vb * 64 + wid * 16 + m16;
        short8 h0 = {0,0,0,0,0,0,0,0}, h1 = {0,0,0,0,0,0,0,0};
        if (node < N_NODES){
            const float* hp = hx + ((size_t)node << 6) + grp * 8;
            h0 = pack_bf8(*(const float4*)hp, *(const float4*)(hp + 4));
            h1 = pack_bf8(*(const float4*)(hp + 32), *(const float4*)(hp + 36));
        }
        #pragma unroll
        for (int TB = 0; TB < 64; TB += 16){
            short8 c0 = *(const short8*)(b2t + (TB + m16) * 64 + grp * 8);
            short8 c1 = *(const short8*)(b2t + (TB + m16) * 64 + 32 + grp * 8);
            f32x4 acc = {0.f, 0.f, 0.f, 0.f};
            acc = __builtin_amdgcn_mfma_f32_16x16x32_bf16(c0, h0, acc, 0, 0, 0);
            acc = __builtin_amdgcn_mfma_f32_16x16x32_bf16(c1, h1, acc, 0, 0, 0);
            if (node < N_NODES) *(f32x4*)(p.hb2 + ((size_t)node << 6) + TB + grp * 4) = acc;
        }
        f32x4 z = {0.f, 0.f, 0.f, 0.f};
        #pragma unroll
        for (int q = 0; q < 4; ++q){
            int chunk = q * 256 + tid;
            int n = vb * 64 + (chunk >> 4), c = (chunk & 15) * 4;
            if (n < N_NODES) *(f32x4*)(p.agg + ((size_t)n << 6) + c) = z;
        }
    } else {
        int g = vb - NBH2;
        int bx = g >> 3, by = g & 7;
        int n0 = bx * 64;
        int cb = by * 512;

        short8 bf0[4], bf1[4];
        #pragma unroll
        for (int ng = 0; ng < 4; ++ng){
            int node = n0 + ng * 16 + m16;
            short8 b0 = {0,0,0,0,0,0,0,0}, b1v = {0,0,0,0,0,0,0,0};
            if (node < N_NODES){
                const float* hp = hx + ((size_t)node << 6) + grp * 8;
                b0  = pack_bf8(*(const float4*)hp, *(const float4*)(hp + 4));
                b1v = pack_bf8(*(const float4*)(hp + 32), *(const float4*)(hp + 36));
            }
            bf0[ng] = b0; bf1[ng] = b1v;
        }
        #pragma unroll
        for (int t = 0; t < 8; ++t){
            int TB = cb + t * 64 + wid * 16;
            const unsigned short* ap = w2t + ((size_t)(TB + m16) << 6) + grp * 8;
            short8 a0 = *(const short8*)ap;
            short8 a1 = *(const short8*)(ap + 32);
            int colLocal = t * 64 + wid * 16 + grp * 4;
            #pragma unroll
            for (int ng = 0; ng < 4; ++ng){
                f32x4 acc = {0.f, 0.f, 0.f, 0.f};
                acc = __builtin_amdgcn_mfma_f32_16x16x32_bf16(a0, bf0[ng], acc, 0, 0, 0);
                acc = __builtin_amdgcn_mfma_f32_16x16x32_bf16(a1, bf1[ng], acc, 0, 0, 0);
                int pk = __builtin_amdgcn_cvt_pk_fp8_f32(acc[0], acc[1], 0, false);
                pk = __builtin_amdgcn_cvt_pk_fp8_f32(acc[2], acc[3], pk, true);
                int row = ng * 16 + m16;
                int dw = ((row << 7) + (colLocal >> 2)) ^ ((row & 7) << 2);
                sm.stgu[dw] = (unsigned)pk;
            }
        }
        __syncthreads();
        #pragma unroll
        for (int s2 = 0; s2 < 8; ++s2){
            int ci = s2 * 256 + tid;
            int row = ci >> 5;
            int c = ci & 31;
            int node = n0 + row;
            int dwb = ((row << 7) + (c << 2)) ^ ((row & 7) << 2);
            uint4 v = *(const uint4*)&sm.stgu[dwb];
            if (node < N_NODES)
                *(uint4*)(p.G + (size_t)node * 4096 + cb + c * 16) = v;
        }
        __syncthreads();
    }
}

__device__ __forceinline__ void msg_body(const P& p, SMu& sm, int vb, int tid,
                                         const unsigned short* tp){
    int w = tid >> 6, o = tid & 63;
    int s = vb * 4 + w;                        // 2500*4 = 10000 exact
    int r0 = p.rowptr[s], r1 = p.rowptr[s + 1];
    if (r0 == r1) return;                      // no barriers below: safe
    MsgSm& ms = sm.mw[w];
    const uint4* gs = (const uint4*)(p.G + (size_t)s * 4096);
    uint4* gld = (uint4*)ms.gl;
    #pragma unroll
    for (int i = 0; i < 4; ++i) gld[i * 64 + o] = gs[i * 64 + o];
    float g[64];
    #pragma unroll
    for (int k = 0; k < 64; k += 2){
        unsigned b0 = ms.gl[(k << 6) + o];
        unsigned b1 = ms.gl[((k + 1) << 6) + o];
        f32x2 d = __builtin_amdgcn_cvt_pk_f32_fp8((int)(b0 | (b1 << 8)), false);
        g[k] = d[0]; g[k + 1] = d[1];
    }
    float hb = p.hb2[((size_t)s << 6) + o];
    for (int j = r0; j < r1; ++j){
        int e = p.eidx[j];
        ms.ts[o] = tp[((size_t)e << 6) + o];
        float acc = hb;
        #pragma unroll
        for (int k8 = 0; k8 < 8; ++k8){
            short8 tv = *(const short8*)&ms.ts[k8 * 8];
            #pragma unroll
            for (int u = 0; u < 8; ++u) acc += bf2f((unsigned short)tv[u]) * g[k8 * 8 + u];
        }
        atomicAdd(&p.agg[((size_t)p.dsts[j] << 6) + o], acc);
    }
}

template<int L2>
__device__ __forceinline__ void combine_body(const P& p, SMu& sm, int vb, int tid,
        const float* hx, const unsigned short* rootT, const float* bias, float* outp){
    int wid = tid >> 6, l = tid & 63;
    int m16 = l & 15, grp = l >> 4;
    int node = vb * 64 + wid * 16 + m16;
    int lnode = wid * 16 + m16;
    bool ok = node < N_NODES;
    short8 h0 = {0,0,0,0,0,0,0,0}, h1 = {0,0,0,0,0,0,0,0};
    if (ok){
        const float* hp = hx + ((size_t)node << 6) + grp * 8;
        h0 = pack_bf8(*(const float4*)hp, *(const float4*)(hp + 4));
        h1 = pack_bf8(*(const float4*)(hp + 32), *(const float4*)(hp + 36));
    }
    #pragma unroll
    for (int TB = 0; TB < 64; TB += 16){
        short8 c0 = *(const short8*)(rootT + (TB + m16) * 64 + grp * 8);
        short8 c1 = *(const short8*)(rootT + (TB + m16) * 64 + 32 + grp * 8);
        f32x4 acc;
        if (ok){
            f32x4 av = *(const f32x4*)(p.agg + ((size_t)node << 6) + TB + grp * 4);
            f32x4 bv = *(const f32x4*)(bias + TB + grp * 4);
            acc[0] = av[0] + bv[0]; acc[1] = av[1] + bv[1];
            acc[2] = av[2] + bv[2]; acc[3] = av[3] + bv[3];
        } else {
            acc[0] = acc[1] = acc[2] = acc[3] = 0.f;
        }
        acc = __builtin_amdgcn_mfma_f32_16x16x32_bf16(c0, h0, acc, 0, 0, 0);
        acc = __builtin_amdgcn_mfma_f32_16x16x32_bf16(c1, h1, acc, 0, 0, 0);
        if (L2){
            #pragma unroll
            for (int r = 0; r < 4; ++r) sm.otile[lnode][TB + grp * 4 + r] = lrelu(acc[r]);
        } else if (ok){
            f32x4 rv;
            rv[0] = lrelu(acc[0]); rv[1] = lrelu(acc[1]);
            rv[2] = lrelu(acc[2]); rv[3] = lrelu(acc[3]);
            *(f32x4*)(outp + ((size_t)node << 6) + TB + grp * 4) = rv;
        }
    }
    if (L2){
        __syncthreads();
        #pragma unroll
        for (int q = 0; q < 16; ++q){
            int ln = wid * 16 + q;
            int n = vb * 64 + ln;
            if (n < N_NODES)
                atomicAdd(&p.hg[p.batch[n] * 64 + l], sm.otile[ln][l]);
        }
        __syncthreads();
    }
}

__device__ __forceinline__ void head_body(const P& p, int tid){
    if (tid >= 64) return;
    const float* row = p.hg + tid * 64;
    float h1[32];
    #pragma unroll
    for (int j = 0; j < 32; ++j){
        float a = p.fc1b[j];
        #pragma unroll 8
        for (int i = 0; i < 64; ++i) a += row[i] * p.fc1w[i * 32 + j];
        h1[j] = lrelu(a);
    }
    float o = p.fc2b[0];
    #pragma unroll
    for (int j = 0; j < 32; ++j) o += h1[j] * p.fc2w[j];
    p.out[tid] = o;
}

// ================= cooperative mega-kernel =================
#define MEGA_GRID 768
__global__ void __launch_bounds__(256, 4) mega_kernel(P p){
    cg::grid_group grid = cg::this_grid();
    __shared__ SMu sm;
    int tid = threadIdx.x;
    int nb = gridDim.x, b0 = blockIdx.x;

    for (int vb = b0; vb < 47; vb += nb) init_body(p, vb, tid);
    __threadfence(); grid.sync();
    for (int vb = b0; vb < PRE_NVB; vb += nb) pre_body(p, sm, vb, tid);
    __threadfence(); grid.sync();
    if (b0 == 0) scan_body(p, sm, tid);
    __threadfence(); grid.sync();
    for (int vb = b0; vb < LA_NVB + 250; vb += nb){
        if (vb < LA_NVB) layerA_body(p, sm, vb, tid, p.hx1, p.b2t1, p.w2t1);
        else             scatter_body(p, vb - LA_NVB, tid);
    }
    __threadfence(); grid.sync();
    for (int vb = b0; vb < 2500; vb += nb) msg_body(p, sm, vb, tid, p.tp1);
    __threadfence(); grid.sync();
    for (int vb = b0; vb < 157; vb += nb) combine_body<0>(p, sm, vb, tid, p.hx1, p.rootT1, p.g1bias, p.hx2);
    __threadfence(); grid.sync();
    for (int vb = b0; vb < LA_NVB; vb += nb) layerA_body(p, sm, vb, tid, p.hx2, p.b2t2, p.w2t2);
    __threadfence(); grid.sync();
    for (int vb = b0; vb < 2500; vb += nb) msg_body(p, sm, vb, tid, p.tp2);
    __threadfence(); grid.sync();
    for (int vb = b0; vb < 157; vb += nb) combine_body<1>(p, sm, vb, tid, p.hx2, p.rootT2, p.g2bias, nullptr);
    __threadfence(); grid.sync();
    if (b0 == 0) head_body(p, tid);
}

// ================= fallback kernels (proven R16 path) =================
__global__ void __launch_bounds__(256) fb_init(P p){ init_body(p, blockIdx.x, threadIdx.x); }
__global__ void __launch_bounds__(256) fb_pre(P p){
    __shared__ SMu sm;
    pre_body(p, sm, blockIdx.x, threadIdx.x);
}
__global__ void __launch_bounds__(256) fb_scan(P p){
    __shared__ SMu sm;
    scan_body(p, sm, threadIdx.x);
}
template<int SCAT>
__global__ void __launch_bounds__(256) fb_layerA(P p, const float* hx,
        const unsigned short* b2t, const unsigned short* w2t){
    __shared__ SMu sm;
    int b = blockIdx.x;
    if (b < LA_NVB) layerA_body(p, sm, b, threadIdx.x, hx, b2t, w2t);
    else if (SCAT)  scatter_body(p, b - LA_NVB, threadIdx.x);
}
__global__ void __launch_bounds__(256) fb_msg(P p, const unsigned short* tp){
    __shared__ SMu sm;
    msg_body(p, sm, blockIdx.x, threadIdx.x, tp);
}
template<int L2>
__global__ void __launch_bounds__(256) fb_combine(P p, const float* hx,
        const unsigned short* rootT, const float* bias, float* outp){
    __shared__ SMu sm;
    combine_body<L2>(p, sm, blockIdx.x, threadIdx.x, hx, rootT, bias, outp);
}
__global__ void fb_head(P p){ head_body(p, threadIdx.x); }

extern "C" void kernel_launch(void* const* d_in, const int* in_sizes, int n_in,
                              void* d_out, int out_size, void* d_ws, size_t ws_size,
                              hipStream_t stream){
    P p;
    p.x      = (const float*)d_in[0];
    const int* ei = (const int*)d_in[1];
    p.src = ei; p.dst = ei + N_EDGES;
    p.ea     = (const float*)d_in[2];
    p.batch  = (const int*)  d_in[3];
    p.nfc_w  = (const float*)d_in[4];
    p.nfc_b  = (const float*)d_in[5];
    p.e1w1   = (const float*)d_in[6];
    p.e1b1   = (const float*)d_in[7];
    p.e1w2   = (const float*)d_in[8];
    p.e1b2   = (const float*)d_in[9];
    p.g1root = (const float*)d_in[10];
    p.g1bias = (const float*)d_in[11];
    p.e2w1   = (const float*)d_in[12];
    p.e2b1   = (const float*)d_in[13];
    p.e2w2   = (const float*)d_in[14];
    p.e2b2   = (const float*)d_in[15];
    p.g2root = (const float*)d_in[16];
    p.g2bias = (const float*)d_in[17];
    p.fc1w   = (const float*)d_in[18];
    p.fc1b   = (const float*)d_in[19];
    p.fc2w   = (const float*)d_in[20];
    p.fc2b   = (const float*)d_in[21];
    p.out    = (float*)d_out;

    char* ws = (char*)d_ws;
    p.hx1 = (float*)ws;               ws += (size_t)N_NODES * 64 * 4;
    p.hx2 = (float*)ws;               ws += (size_t)N_NODES * 64 * 4;
    p.tp1 = (unsigned short*)ws;      ws += (size_t)N_EDGES * 64 * 2;
    p.tp2 = (unsigned short*)ws;      ws += (size_t)N_EDGES * 64 * 2;
    p.hb2 = (float*)ws;               ws += (size_t)N_NODES * 64 * 4;
    p.agg = (float*)ws;               ws += (size_t)N_NODES * 64 * 4;
    p.hg  = (float*)ws;               ws += (size_t)N_GRAPHS * 64 * 4;
    p.w2t1 = (unsigned short*)ws;     ws += (size_t)64 * 64 * 64 * 2;
    p.w2t2 = (unsigned short*)ws;     ws += (size_t)64 * 64 * 64 * 2;
    p.nfc_wt = (unsigned short*)ws;   ws += (size_t)8192 * 2;
    p.w1t1 = (unsigned short*)ws;     ws += (size_t)2048 * 2;
    p.w1t2 = (unsigned short*)ws;     ws += (size_t)2048 * 2;
    p.b2t1 = (unsigned short*)ws;     ws += (size_t)4096 * 2;
    p.b2t2 = (unsigned short*)ws;     ws += (size_t)4096 * 2;
    p.rootT1 = (unsigned short*)ws;   ws += (size_t)4096 * 2;
    p.rootT2 = (unsigned short*)ws;   ws += (size_t)4096 * 2;
    p.counts = (int*)ws;              ws += (size_t)10240 * 4;
    p.cursor = (int*)ws;              ws += (size_t)10240 * 4;
    p.rowptr = (int*)ws;              ws += (size_t)10240 * 4;
    p.eidx   = (int*)ws;              ws += (size_t)N_EDGES * 4;
    p.dsts   = (int*)ws;              ws += (size_t)N_EDGES * 4;
    p.G = (unsigned char*)ws;         // 41 MB fp8

    void* kargs[] = { &p };
    hipError_t err = hipLaunchCooperativeKernel((const void*)mega_kernel,
                                                dim3(MEGA_GRID), dim3(256),
                                                kargs, 0, stream);
    if (err != hipSuccess){
        // fallback: proven 10-kernel pipeline (R16, 215 µs)
        fb_init<<<47, 256, 0, stream>>>(p);
        fb_pre<<<PRE_NVB, 256, 0, stream>>>(p);
        fb_scan<<<1, 256, 0, stream>>>(p);
        fb_layerA<1><<<LA_NVB + 250, 256, 0, stream>>>(p, p.hx1, p.b2t1, p.w2t1);
        fb_msg<<<2500, 256, 0, stream>>>(p, p.tp1);
        fb_combine<0><<<157, 256, 0, stream>>>(p, p.hx1, p.rootT1, p.g1bias, p.hx2);
        fb_layerA<0><<<LA_NVB, 256, 0, stream>>>(p, p.hx2, p.b2t2, p.w2t2);
        fb_msg<<<2500, 256, 0, stream>>>(p, p.tp2);
        fb_combine<1><<<157, 256, 0, stream>>>(p, p.hx2, p.rootT2, p.g2bias, nullptr);
        fb_head<<<1, 64, 0, stream>>>(p);
    }
}

// Round 18
// 232.894 us; speedup vs baseline: 7.0752x; 7.0752x over previous
//
#include <hip/hip_runtime.h>
#include <hip/hip_bf16.h>

#define N_NODES  10000
#define N_EDGES  64000
#define N_GRAPHS 64
#define HID      64

typedef __attribute__((ext_vector_type(8))) short short8;
typedef __attribute__((ext_vector_type(4))) float f32x4;
typedef __attribute__((ext_vector_type(2))) float f32x2;

__device__ __forceinline__ float lrelu(float v){ return v > 0.f ? v : 0.01f*v; }

__device__ __forceinline__ unsigned short f2bf(float f){
    union { float f; unsigned u; } v; v.f = f;
    unsigned r = v.u + 0x7fff + ((v.u >> 16) & 1);
    return (unsigned short)(r >> 16);
}
__device__ __forceinline__ float bf2f(unsigned short s){
    union { unsigned u; float f; } v; v.u = ((unsigned)s) << 16;
    return v.f;
}
__device__ __forceinline__ short8 pack_bf8(float4 a, float4 b){
    short8 r;
    r[0]=(short)f2bf(a.x); r[1]=(short)f2bf(a.y); r[2]=(short)f2bf(a.z); r[3]=(short)f2bf(a.w);
    r[4]=(short)f2bf(b.x); r[5]=(short)f2bf(b.y); r[6]=(short)f2bf(b.z); r[7]=(short)f2bf(b.w);
    return r;
}

// ---------------- init: zero counts+hg | all small weight transposes (bf16) ----------------
__global__ void __launch_bounds__(256) init_kernel(
        int* __restrict__ counts, float* __restrict__ hg,
        const float* __restrict__ nfc_w, unsigned short* __restrict__ nfc_wt,
        const float* __restrict__ e1w1, unsigned short* __restrict__ w1t1,
        const float* __restrict__ e2w1, unsigned short* __restrict__ w1t2,
        const float* __restrict__ e1b2, unsigned short* __restrict__ b2t1,
        const float* __restrict__ e2b2, unsigned short* __restrict__ b2t2,
        const float* __restrict__ g1root, unsigned short* __restrict__ rootT1,
        const float* __restrict__ g2root, unsigned short* __restrict__ rootT2){
    int b = blockIdx.x, tid = threadIdx.x;
    if (b < 40){
        int i = b * 256 + tid;
        if (i < N_NODES) counts[i] = 0;
        if (b < 16) hg[b * 256 + tid] = 0.f;
    } else if (b == 40){
        for (int idx = tid; idx < 8192; idx += 256){
            int o = idx >> 7, i = idx & 127;
            nfc_wt[idx] = f2bf(nfc_w[i * 64 + o]);
        }
    } else if (b <= 42){
        const float* w1 = (b == 42) ? e2w1 : e1w1;
        unsigned short* w1t = (b == 42) ? w1t2 : w1t1;
        for (int idx = tid; idx < 2048; idx += 256){
            int o = idx >> 5, k = idx & 31;
            w1t[idx] = f2bf(w1[k * 64 + o]);
        }
    } else if (b <= 44){
        const float* b2 = (b == 44) ? e2b2 : e1b2;
        unsigned short* b2t = (b == 44) ? b2t2 : b2t1;
        for (int idx = tid; idx < 4096; idx += 256){
            int o = idx >> 6, i = idx & 63;
            b2t[idx] = f2bf(b2[i * 64 + o]);
        }
    } else {
        const float* rt = (b == 46) ? g2root : g1root;
        unsigned short* rT = (b == 46) ? rootT2 : rootT1;
        for (int idx = tid; idx < 4096; idx += 256){
            int o = idx >> 6, i = idx & 63;
            rT[idx] = f2bf(rt[i * 64 + o]);
        }
    }
}

// ---------------- pre: nodeFC (MFMA) | both t-GEMMs (MFMA, orig order) | w2conv | count ----
#define PRE_NFC 157
#define PRE_TG  1000
#define PRE_W2C 128
#define PRE_CNT 250
__global__ void __launch_bounds__(256) pre_kernel(
        const float* __restrict__ x, const unsigned short* __restrict__ nfc_wt,
        const float* __restrict__ nfc_b, float* __restrict__ hx1,
        const float* __restrict__ ea,
        const unsigned short* __restrict__ w1t1, const float* __restrict__ e1b1, unsigned short* __restrict__ tp1,
        const unsigned short* __restrict__ w1t2, const float* __restrict__ e2b1, unsigned short* __restrict__ tp2,
        const float* __restrict__ e1w2, unsigned short* __restrict__ w2t1,
        const float* __restrict__ e2w2, unsigned short* __restrict__ w2t2,
        const int* __restrict__ src, int* __restrict__ counts){
    __shared__ float tile[64][65];
    int b = blockIdx.x, tid = threadIdx.x;
    int wid = tid >> 6, l = tid & 63;
    int m16 = l & 15, grp = l >> 4;
    if (b < PRE_NFC){
        int node = b * 64 + wid * 16 + m16;
        bool ok = node < N_NODES;
        short8 xb[4];
        #pragma unroll
        for (int kq = 0; kq < 4; ++kq){
            if (ok){
                const float* xp = x + (size_t)node * 128 + kq * 32 + grp * 8;
                xb[kq] = pack_bf8(*(const float4*)xp, *(const float4*)(xp + 4));
            } else {
                short8 z = {0,0,0,0,0,0,0,0}; xb[kq] = z;
            }
        }
        #pragma unroll
        for (int TB = 0; TB < 64; TB += 16){
            f32x4 acc = *(const f32x4*)(nfc_b + TB + grp * 4);
            #pragma unroll
            for (int kq = 0; kq < 4; ++kq){
                short8 af = *(const short8*)(nfc_wt + (TB + m16) * 128 + kq * 32 + grp * 8);
                acc = __builtin_amdgcn_mfma_f32_16x16x32_bf16(af, xb[kq], acc, 0, 0, 0);
            }
            f32x4 r;
            r[0] = lrelu(acc[0]); r[1] = lrelu(acc[1]); r[2] = lrelu(acc[2]); r[3] = lrelu(acc[3]);
            if (ok) *(f32x4*)(hx1 + ((size_t)node << 6) + TB + grp * 4) = r;
        }
    } else if (b < PRE_NFC + PRE_TG){
        int j = (b - PRE_NFC) * 64 + wid * 16 + m16;
        const float* row = ea + (size_t)j * 32 + grp * 8;
        short8 ef = pack_bf8(*(const float4*)row, *(const float4*)(row + 4));
        #pragma unroll
        for (int TB = 0; TB < 64; TB += 16){
            short8 wf1 = *(const short8*)(w1t1 + (TB + m16) * 32 + grp * 8);
            f32x4 a1 = *(const f32x4*)(e1b1 + TB + grp * 4);
            a1 = __builtin_amdgcn_mfma_f32_16x16x32_bf16(wf1, ef, a1, 0, 0, 0);
            uint2 p;
            p.x = (unsigned)f2bf(fmaxf(a1[0], 0.f)) | ((unsigned)f2bf(fmaxf(a1[1], 0.f)) << 16);
            p.y = (unsigned)f2bf(fmaxf(a1[2], 0.f)) | ((unsigned)f2bf(fmaxf(a1[3], 0.f)) << 16);
            *(uint2*)(tp1 + ((size_t)j << 6) + TB + grp * 4) = p;
            short8 wf2 = *(const short8*)(w1t2 + (TB + m16) * 32 + grp * 8);
            f32x4 a2 = *(const f32x4*)(e2b1 + TB + grp * 4);
            a2 = __builtin_amdgcn_mfma_f32_16x16x32_bf16(wf2, ef, a2, 0, 0, 0);
            p.x = (unsigned)f2bf(fmaxf(a2[0], 0.f)) | ((unsigned)f2bf(fmaxf(a2[1], 0.f)) << 16);
            p.y = (unsigned)f2bf(fmaxf(a2[2], 0.f)) | ((unsigned)f2bf(fmaxf(a2[3], 0.f)) << 16);
            *(uint2*)(tp2 + ((size_t)j << 6) + TB + grp * 4) = p;
        }
    } else if (b < PRE_NFC + PRE_TG + PRE_W2C){
        int bb = b - PRE_NFC - PRE_TG;
        int k = bb & 63;
        const float* srcw = ((bb < 64) ? e1w2 : e2w2) + (size_t)k * 4096;
        unsigned short* dstw = (bb < 64) ? w2t1 : w2t2;
        for (int idx = tid; idx < 4096; idx += 256) tile[idx >> 6][idx & 63] = srcw[idx];
        __syncthreads();
        for (int idx = tid; idx < 4096; idx += 256){
            int o = idx >> 6, i = idx & 63;
            dstw[((size_t)(k * 64 + o) << 6) + i] = f2bf(tile[i][o]);
        }
    } else {
        int e = (b - PRE_NFC - PRE_TG - PRE_W2C) * 256 + tid;
        if (e < N_EDGES) atomicAdd(&counts[src[e]], 1);
    }
}

// scan rowptr from counts (plain loads — kernel boundary gives coherence); zero cursor
__global__ void csr_scan_kernel(const int* __restrict__ counts, int* __restrict__ rowptr,
                                int* __restrict__ cursor){
    __shared__ int part[256];
    int tid = threadIdx.x;
    const int CH = (N_NODES + 255) / 256;      // 40
    int base = tid * CH, s = 0;
    for (int i = 0; i < CH; ++i){ int idx = base + i; if (idx < N_NODES){ cursor[idx] = 0; s += counts[idx]; } }
    part[tid] = s; __syncthreads();
    for (int off = 1; off < 256; off <<= 1){
        int v = (tid >= off) ? part[tid - off] : 0;
        __syncthreads();
        part[tid] += v;
        __syncthreads();
    }
    int run = part[tid] - s;
    for (int i = 0; i < CH; ++i){ int idx = base + i; if (idx < N_NODES){ rowptr[idx] = run; run += counts[idx]; } }
    if (tid == 255) rowptr[N_NODES] = run;
}

// ---------------- per-layer: hb2(MFMA)+agg0 | gmat (MFMA -> fp8 G) | scatter ---------------
#define NBH2 157
#define NBG  (157 * 8)
template<int SCAT>
__global__ void __launch_bounds__(256) layerA_kernel(
        const float* __restrict__ hx, const unsigned short* __restrict__ b2t,
        float* __restrict__ hb2, float* __restrict__ agg,
        const unsigned short* __restrict__ w2t, unsigned char* __restrict__ G,
        const int* __restrict__ src, const int* __restrict__ dst,
        const int* __restrict__ rowptr, int* __restrict__ cursor,
        int* __restrict__ eidx, int* __restrict__ dsts){
    __shared__ unsigned stgu[8192];            // 32 KB (gmat branch only)
    int b = blockIdx.x, tid = threadIdx.x;
    int wid = tid >> 6, l = tid & 63;
    int m16 = l & 15, grp = l >> 4;

    if (b < NBH2){
        int node = b * 64 + wid * 16 + m16;
        short8 h0 = {0,0,0,0,0,0,0,0}, h1 = {0,0,0,0,0,0,0,0};
        if (node < N_NODES){
            const float* hp = hx + ((size_t)node << 6) + grp * 8;
            h0 = pack_bf8(*(const float4*)hp, *(const float4*)(hp + 4));
            h1 = pack_bf8(*(const float4*)(hp + 32), *(const float4*)(hp + 36));
        }
        #pragma unroll
        for (int TB = 0; TB < 64; TB += 16){
            short8 c0 = *(const short8*)(b2t + (TB + m16) * 64 + grp * 8);
            short8 c1 = *(const short8*)(b2t + (TB + m16) * 64 + 32 + grp * 8);
            f32x4 acc = {0.f, 0.f, 0.f, 0.f};
            acc = __builtin_amdgcn_mfma_f32_16x16x32_bf16(c0, h0, acc, 0, 0, 0);
            acc = __builtin_amdgcn_mfma_f32_16x16x32_bf16(c1, h1, acc, 0, 0, 0);
            if (node < N_NODES) *(f32x4*)(hb2 + ((size_t)node << 6) + TB + grp * 4) = acc;
        }
        f32x4 z = {0.f, 0.f, 0.f, 0.f};
        #pragma unroll
        for (int q = 0; q < 4; ++q){
            int chunk = q * 256 + tid;
            int n = b * 64 + (chunk >> 4), c = (chunk & 15) * 4;
            if (n < N_NODES) *(f32x4*)(agg + ((size_t)n << 6) + c) = z;
        }
    } else if (b < NBH2 + NBG){
        int g = b - NBH2;
        int bx = g >> 3, by = g & 7;
        int n0 = bx * 64;
        int cb = by * 512;

        short8 bf0[4], bf1[4];
        #pragma unroll
        for (int ng = 0; ng < 4; ++ng){
            int node = n0 + ng * 16 + m16;
            short8 b0 = {0,0,0,0,0,0,0,0}, b1v = {0,0,0,0,0,0,0,0};
            if (node < N_NODES){
                const float* hp = hx + ((size_t)node << 6) + grp * 8;
                b0  = pack_bf8(*(const float4*)hp, *(const float4*)(hp + 4));
                b1v = pack_bf8(*(const float4*)(hp + 32), *(const float4*)(hp + 36));
            }
            bf0[ng] = b0; bf1[ng] = b1v;
        }

        #pragma unroll
        for (int t = 0; t < 8; ++t){
            int TB = cb + t * 64 + wid * 16;
            const unsigned short* ap = w2t + ((size_t)(TB + m16) << 6) + grp * 8;
            short8 a0 = *(const short8*)ap;
            short8 a1 = *(const short8*)(ap + 32);
            int colLocal = t * 64 + wid * 16 + grp * 4;
            #pragma unroll
            for (int ng = 0; ng < 4; ++ng){
                f32x4 acc = {0.f, 0.f, 0.f, 0.f};
                acc = __builtin_amdgcn_mfma_f32_16x16x32_bf16(a0, bf0[ng], acc, 0, 0, 0);
                acc = __builtin_amdgcn_mfma_f32_16x16x32_bf16(a1, bf1[ng], acc, 0, 0, 0);
                int pk = __builtin_amdgcn_cvt_pk_fp8_f32(acc[0], acc[1], 0, false);
                pk = __builtin_amdgcn_cvt_pk_fp8_f32(acc[2], acc[3], pk, true);
                int row = ng * 16 + m16;
                int dw = ((row << 7) + (colLocal >> 2)) ^ ((row & 7) << 2);
                stgu[dw] = (unsigned)pk;
            }
        }
        __syncthreads();
        #pragma unroll
        for (int s2 = 0; s2 < 8; ++s2){
            int ci = s2 * 256 + tid;
            int row = ci >> 5;
            int c = ci & 31;
            int node = n0 + row;
            int dwb = ((row << 7) + (c << 2)) ^ ((row & 7) << 2);
            uint4 v = *(const uint4*)&stgu[dwb];
            if (node < N_NODES)
                *(uint4*)(G + (size_t)node * 4096 + cb + c * 16) = v;
        }
    } else if (SCAT){
        int e = (b - NBH2 - NBG) * 256 + tid;
        if (e < N_EDGES){
            int s = src[e];
            int j = rowptr[s] + atomicAdd(&cursor[s], 1);
            eidx[j] = e; dsts[j] = dst[e];
        }
    }
}

// ---------------- msg: 4 waves/block, per-wave LDS; G row via coalesced uint4 loads -------
struct MsgSm {
    unsigned char gl[4096] __attribute__((aligned(16)));
    unsigned short ts[64] __attribute__((aligned(16)));
};
__global__ void __launch_bounds__(256) msg_csr_kernel(
        const unsigned short* __restrict__ tp, const unsigned char* __restrict__ G,
        const float* __restrict__ hb2, const int* __restrict__ rowptr,
        const int* __restrict__ eidx, const int* __restrict__ dsts,
        float* __restrict__ agg){
    __shared__ MsgSm mw[4];
    int tid = threadIdx.x;
    int w = tid >> 6, o = tid & 63;
    int s = blockIdx.x * 4 + w;                // 2500*4 = 10000 exact
    int r0 = rowptr[s], r1 = rowptr[s + 1];
    if (r0 == r1) return;                      // no barriers in this kernel: safe
    MsgSm& ms = mw[w];
    const uint4* gs = (const uint4*)(G + (size_t)s * 4096);
    uint4* gld = (uint4*)ms.gl;
    #pragma unroll
    for (int i = 0; i < 4; ++i) gld[i * 64 + o] = gs[i * 64 + o];
    float g[64];
    #pragma unroll
    for (int k = 0; k < 64; k += 2){
        unsigned b0 = ms.gl[(k << 6) + o];
        unsigned b1 = ms.gl[((k + 1) << 6) + o];
        f32x2 d = __builtin_amdgcn_cvt_pk_f32_fp8((int)(b0 | (b1 << 8)), false);
        g[k] = d[0]; g[k + 1] = d[1];
    }
    float hb = hb2[((size_t)s << 6) + o];
    for (int j = r0; j < r1; ++j){
        int e = eidx[j];
        ms.ts[o] = tp[((size_t)e << 6) + o];
        float acc = hb;
        #pragma unroll
        for (int k8 = 0; k8 < 8; ++k8){
            short8 tv = *(const short8*)&ms.ts[k8 * 8];
            #pragma unroll
            for (int u = 0; u < 8; ++u) acc += bf2f((unsigned short)tv[u]) * g[k8 * 8 + u];
        }
        atomicAdd(&agg[((size_t)dsts[j] << 6) + o], acc);
    }
}

// ---------------- combine (MFMA root GEMM); L2: LDS-staged conflict-free pooling ----------
template<int L2>
__global__ void __launch_bounds__(256) combine_kernel(
        const float* __restrict__ agg, const float* __restrict__ hx,
        const unsigned short* __restrict__ rootT, const float* __restrict__ bias,
        float* __restrict__ outp, const int* __restrict__ batch, float* __restrict__ hg){
    __shared__ float otile[64][65];
    int b = blockIdx.x, tid = threadIdx.x;
    int wid = tid >> 6, l = tid & 63;
    int m16 = l & 15, grp = l >> 4;
    int node = b * 64 + wid * 16 + m16;
    int lnode = wid * 16 + m16;
    bool ok = node < N_NODES;
    short8 h0 = {0,0,0,0,0,0,0,0}, h1 = {0,0,0,0,0,0,0,0};
    if (ok){
        const float* hp = hx + ((size_t)node << 6) + grp * 8;
        h0 = pack_bf8(*(const float4*)hp, *(const float4*)(hp + 4));
        h1 = pack_bf8(*(const float4*)(hp + 32), *(const float4*)(hp + 36));
    }
    #pragma unroll
    for (int TB = 0; TB < 64; TB += 16){
        short8 c0 = *(const short8*)(rootT + (TB + m16) * 64 + grp * 8);
        short8 c1 = *(const short8*)(rootT + (TB + m16) * 64 + 32 + grp * 8);
        f32x4 acc;
        if (ok){
            f32x4 av = *(const f32x4*)(agg + ((size_t)node << 6) + TB + grp * 4);
            f32x4 bv = *(const f32x4*)(bias + TB + grp * 4);
            acc[0] = av[0] + bv[0]; acc[1] = av[1] + bv[1];
            acc[2] = av[2] + bv[2]; acc[3] = av[3] + bv[3];
        } else {
            acc[0] = acc[1] = acc[2] = acc[3] = 0.f;
        }
        acc = __builtin_amdgcn_mfma_f32_16x16x32_bf16(c0, h0, acc, 0, 0, 0);
        acc = __builtin_amdgcn_mfma_f32_16x16x32_bf16(c1, h1, acc, 0, 0, 0);
        if (L2){
            #pragma unroll
            for (int r = 0; r < 4; ++r) otile[lnode][TB + grp * 4 + r] = lrelu(acc[r]);
        } else if (ok){
            f32x4 rv;
            rv[0] = lrelu(acc[0]); rv[1] = lrelu(acc[1]);
            rv[2] = lrelu(acc[2]); rv[3] = lrelu(acc[3]);
            *(f32x4*)(outp + ((size_t)node << 6) + TB + grp * 4) = rv;
        }
    }
    if (L2){
        __syncthreads();
        #pragma unroll
        for (int p = 0; p < 16; ++p){
            int ln = wid * 16 + p;
            int n = b * 64 + ln;
            if (n < N_NODES)
                atomicAdd(&hg[batch[n] * 64 + l], otile[ln][l]);
        }
    }
}

__global__ void head_kernel(const float* __restrict__ hg, const float* __restrict__ fc1w,
                            const float* __restrict__ fc1b, const float* __restrict__ fc2w,
                            const float* __restrict__ fc2b, float* __restrict__ out){
    int g = threadIdx.x;
    const float* row = hg + g * 64;
    float h1[32];
    #pragma unroll
    for (int j = 0; j < 32; ++j){
        float a = fc1b[j];
        #pragma unroll 8
        for (int i = 0; i < 64; ++i) a += row[i] * fc1w[i * 32 + j];
        h1[j] = lrelu(a);
    }
    float o = fc2b[0];
    #pragma unroll
    for (int j = 0; j < 32; ++j) o += h1[j] * fc2w[j];
    out[g] = o;
}

extern "C" void kernel_launch(void* const* d_in, const int* in_sizes, int n_in,
                              void* d_out, int out_size, void* d_ws, size_t ws_size,
                              hipStream_t stream){
    const float* x      = (const float*)d_in[0];
    const int*   ei     = (const int*)  d_in[1];
    const float* ea     = (const float*)d_in[2];
    const int*   batch  = (const int*)  d_in[3];
    const float* nfc_w  = (const float*)d_in[4];
    const float* nfc_b  = (const float*)d_in[5];
    const float* e1w1   = (const float*)d_in[6];
    const float* e1b1   = (const float*)d_in[7];
    const float* e1w2   = (const float*)d_in[8];
    const float* e1b2   = (const float*)d_in[9];
    const float* g1root = (const float*)d_in[10];
    const float* g1bias = (const float*)d_in[11];
    const float* e2w1   = (const float*)d_in[12];
    const float* e2b1   = (const float*)d_in[13];
    const float* e2w2   = (const float*)d_in[14];
    const float* e2b2   = (const float*)d_in[15];
    const float* g2root = (const float*)d_in[16];
    const float* g2bias = (const float*)d_in[17];
    const float* fc1w   = (const float*)d_in[18];
    const float* fc1b   = (const float*)d_in[19];
    const float* fc2w   = (const float*)d_in[20];
    const float* fc2b   = (const float*)d_in[21];
    float* out = (float*)d_out;

    const int* src = ei;
    const int* dst = ei + N_EDGES;

    // workspace carve-up
    char* ws = (char*)d_ws;
    float* hx1 = (float*)ws;               ws += (size_t)N_NODES * 64 * 4;
    float* hx2 = (float*)ws;               ws += (size_t)N_NODES * 64 * 4;
    unsigned short* tp1 = (unsigned short*)ws; ws += (size_t)N_EDGES * 64 * 2;
    unsigned short* tp2 = (unsigned short*)ws; ws += (size_t)N_EDGES * 64 * 2;
    float* hb2 = (float*)ws;               ws += (size_t)N_NODES * 64 * 4;
    float* agg = (float*)ws;               ws += (size_t)N_NODES * 64 * 4;
    float* hg  = (float*)ws;               ws += (size_t)N_GRAPHS * 64 * 4;
    unsigned short* w2t1 = (unsigned short*)ws; ws += (size_t)64 * 64 * 64 * 2;
    unsigned short* w2t2 = (unsigned short*)ws; ws += (size_t)64 * 64 * 64 * 2;
    unsigned short* nfc_wt = (unsigned short*)ws; ws += (size_t)8192 * 2;
    unsigned short* w1t1 = (unsigned short*)ws; ws += (size_t)2048 * 2;
    unsigned short* w1t2 = (unsigned short*)ws; ws += (size_t)2048 * 2;
    unsigned short* b2t1 = (unsigned short*)ws; ws += (size_t)4096 * 2;
    unsigned short* b2t2 = (unsigned short*)ws; ws += (size_t)4096 * 2;
    unsigned short* rootT1 = (unsigned short*)ws; ws += (size_t)4096 * 2;
    unsigned short* rootT2 = (unsigned short*)ws; ws += (size_t)4096 * 2;
    int* counts = (int*)ws;                ws += (size_t)10240 * 4;
    int* cursor = (int*)ws;                ws += (size_t)10240 * 4;
    int* rowptr = (int*)ws;                ws += (size_t)10240 * 4;
    int* eidx   = (int*)ws;                ws += (size_t)N_EDGES * 4;
    int* dsts   = (int*)ws;                ws += (size_t)N_EDGES * 4;
    unsigned char* G = (unsigned char*)ws;  // 41 MB fp8

    // 1: init; 2: pre; 3: scan
    init_kernel<<<47, 256, 0, stream>>>(counts, hg, nfc_w, nfc_wt,
        e1w1, w1t1, e2w1, w1t2, e1b2, b2t1, e2b2, b2t2, g1root, rootT1, g2root, rootT2);
    pre_kernel<<<PRE_NFC + PRE_TG + PRE_W2C + PRE_CNT, 256, 0, stream>>>(
        x, nfc_wt, nfc_b, hx1, ea, w1t1, e1b1, tp1, w1t2, e2b1, tp2,
        e1w2, w2t1, e2w2, w2t2, src, counts);
    csr_scan_kernel<<<1, 256, 0, stream>>>(counts, rowptr, cursor);

    // ---------- layer 1 (4,5,6) — scatter folded into layerA as extra parallel blocks ------
    layerA_kernel<1><<<NBH2 + NBG + 250, 256, 0, stream>>>(
        hx1, b2t1, hb2, agg, w2t1, G, src, dst, rowptr, cursor, eidx, dsts);
    msg_csr_kernel<<<2500, 256, 0, stream>>>(tp1, G, hb2, rowptr, eidx, dsts, agg);
    combine_kernel<0><<<157, 256, 0, stream>>>(agg, hx1, rootT1, g1bias, hx2, batch, nullptr);

    // ---------- layer 2 (7,8,9) ----------
    layerA_kernel<0><<<NBH2 + NBG, 256, 0, stream>>>(
        hx2, b2t2, hb2, agg, w2t2, G, src, dst, rowptr, cursor, eidx, dsts);
    msg_csr_kernel<<<2500, 256, 0, stream>>>(tp2, G, hb2, rowptr, eidx, dsts, agg);
    combine_kernel<1><<<157, 256, 0, stream>>>(agg, hx2, rootT2, g2bias, nullptr, batch, hg);

    // 10: head
    head_kernel<<<1, 64, 0, stream>>>(hg, fc1w, fc1b, fc2w, fc2b, out);
}

// Round 19
// 212.984 us; speedup vs baseline: 7.7366x; 1.0935x over previous
//
#include <hip/hip_runtime.h>
#include <hip/hip_bf16.h>

#define N_NODES  10000
#define N_EDGES  64000
#define N_GRAPHS 64
#define HID      64

typedef __attribute__((ext_vector_type(8))) short short8;
typedef __attribute__((ext_vector_type(4))) float f32x4;
typedef __attribute__((ext_vector_type(2))) float f32x2;

__device__ __forceinline__ float lrelu(float v){ return v > 0.f ? v : 0.01f*v; }

__device__ __forceinline__ unsigned short f2bf(float f){
    union { float f; unsigned u; } v; v.f = f;
    unsigned r = v.u + 0x7fff + ((v.u >> 16) & 1);
    return (unsigned short)(r >> 16);
}
__device__ __forceinline__ float bf2f(unsigned short s){
    union { unsigned u; float f; } v; v.u = ((unsigned)s) << 16;
    return v.f;
}
__device__ __forceinline__ short8 pack_bf8(float4 a, float4 b){
    short8 r;
    r[0]=(short)f2bf(a.x); r[1]=(short)f2bf(a.y); r[2]=(short)f2bf(a.z); r[3]=(short)f2bf(a.w);
    r[4]=(short)f2bf(b.x); r[5]=(short)f2bf(b.y); r[6]=(short)f2bf(b.z); r[7]=(short)f2bf(b.w);
    return r;
}

// ---------------- init: zero counts+hg | all small weight transposes (bf16) ----------------
__global__ void __launch_bounds__(256) init_kernel(
        int* __restrict__ counts, float* __restrict__ hg,
        const float* __restrict__ nfc_w, unsigned short* __restrict__ nfc_wt,
        const float* __restrict__ e1w1, unsigned short* __restrict__ w1t1,
        const float* __restrict__ e2w1, unsigned short* __restrict__ w1t2,
        const float* __restrict__ e1b2, unsigned short* __restrict__ b2t1,
        const float* __restrict__ e2b2, unsigned short* __restrict__ b2t2,
        const float* __restrict__ g1root, unsigned short* __restrict__ rootT1,
        const float* __restrict__ g2root, unsigned short* __restrict__ rootT2){
    int b = blockIdx.x, tid = threadIdx.x;
    if (b < 40){
        int i = b * 256 + tid;
        if (i < N_NODES) counts[i] = 0;
        if (b < 16) hg[b * 256 + tid] = 0.f;
    } else if (b == 40){
        for (int idx = tid; idx < 8192; idx += 256){
            int o = idx >> 7, i = idx & 127;
            nfc_wt[idx] = f2bf(nfc_w[i * 64 + o]);
        }
    } else if (b <= 42){
        const float* w1 = (b == 42) ? e2w1 : e1w1;
        unsigned short* w1t = (b == 42) ? w1t2 : w1t1;
        for (int idx = tid; idx < 2048; idx += 256){
            int o = idx >> 5, k = idx & 31;
            w1t[idx] = f2bf(w1[k * 64 + o]);
        }
    } else if (b <= 44){
        const float* b2 = (b == 44) ? e2b2 : e1b2;
        unsigned short* b2t = (b == 44) ? b2t2 : b2t1;
        for (int idx = tid; idx < 4096; idx += 256){
            int o = idx >> 6, i = idx & 63;
            b2t[idx] = f2bf(b2[i * 64 + o]);
        }
    } else {
        const float* rt = (b == 46) ? g2root : g1root;
        unsigned short* rT = (b == 46) ? rootT2 : rootT1;
        for (int idx = tid; idx < 4096; idx += 256){
            int o = idx >> 6, i = idx & 63;
            rT[idx] = f2bf(rt[i * 64 + o]);
        }
    }
}

// ---------------- pre: nodeFC (MFMA) | both t-GEMMs (MFMA, orig order) | w2conv | count ----
#define PRE_NFC 157
#define PRE_TG  1000
#define PRE_W2C 128
#define PRE_CNT 250
__global__ void __launch_bounds__(256) pre_kernel(
        const float* __restrict__ x, const unsigned short* __restrict__ nfc_wt,
        const float* __restrict__ nfc_b, float* __restrict__ hx1,
        const float* __restrict__ ea,
        const unsigned short* __restrict__ w1t1, const float* __restrict__ e1b1, unsigned short* __restrict__ tp1,
        const unsigned short* __restrict__ w1t2, const float* __restrict__ e2b1, unsigned short* __restrict__ tp2,
        const float* __restrict__ e1w2, unsigned short* __restrict__ w2t1,
        const float* __restrict__ e2w2, unsigned short* __restrict__ w2t2,
        const int* __restrict__ src, int* __restrict__ counts){
    __shared__ float tile[64][65];
    int b = blockIdx.x, tid = threadIdx.x;
    int wid = tid >> 6, l = tid & 63;
    int m16 = l & 15, grp = l >> 4;
    if (b < PRE_NFC){
        int node = b * 64 + wid * 16 + m16;
        bool ok = node < N_NODES;
        short8 xb[4];
        #pragma unroll
        for (int kq = 0; kq < 4; ++kq){
            if (ok){
                const float* xp = x + (size_t)node * 128 + kq * 32 + grp * 8;
                xb[kq] = pack_bf8(*(const float4*)xp, *(const float4*)(xp + 4));
            } else {
                short8 z = {0,0,0,0,0,0,0,0}; xb[kq] = z;
            }
        }
        #pragma unroll
        for (int TB = 0; TB < 64; TB += 16){
            f32x4 acc = *(const f32x4*)(nfc_b + TB + grp * 4);
            #pragma unroll
            for (int kq = 0; kq < 4; ++kq){
                short8 af = *(const short8*)(nfc_wt + (TB + m16) * 128 + kq * 32 + grp * 8);
                acc = __builtin_amdgcn_mfma_f32_16x16x32_bf16(af, xb[kq], acc, 0, 0, 0);
            }
            f32x4 r;
            r[0] = lrelu(acc[0]); r[1] = lrelu(acc[1]); r[2] = lrelu(acc[2]); r[3] = lrelu(acc[3]);
            if (ok) *(f32x4*)(hx1 + ((size_t)node << 6) + TB + grp * 4) = r;
        }
    } else if (b < PRE_NFC + PRE_TG){
        int j = (b - PRE_NFC) * 64 + wid * 16 + m16;
        const float* row = ea + (size_t)j * 32 + grp * 8;
        short8 ef = pack_bf8(*(const float4*)row, *(const float4*)(row + 4));
        #pragma unroll
        for (int TB = 0; TB < 64; TB += 16){
            short8 wf1 = *(const short8*)(w1t1 + (TB + m16) * 32 + grp * 8);
            f32x4 a1 = *(const f32x4*)(e1b1 + TB + grp * 4);
            a1 = __builtin_amdgcn_mfma_f32_16x16x32_bf16(wf1, ef, a1, 0, 0, 0);
            uint2 p;
            p.x = (unsigned)f2bf(fmaxf(a1[0], 0.f)) | ((unsigned)f2bf(fmaxf(a1[1], 0.f)) << 16);
            p.y = (unsigned)f2bf(fmaxf(a1[2], 0.f)) | ((unsigned)f2bf(fmaxf(a1[3], 0.f)) << 16);
            *(uint2*)(tp1 + ((size_t)j << 6) + TB + grp * 4) = p;
            short8 wf2 = *(const short8*)(w1t2 + (TB + m16) * 32 + grp * 8);
            f32x4 a2 = *(const f32x4*)(e2b1 + TB + grp * 4);
            a2 = __builtin_amdgcn_mfma_f32_16x16x32_bf16(wf2, ef, a2, 0, 0, 0);
            p.x = (unsigned)f2bf(fmaxf(a2[0], 0.f)) | ((unsigned)f2bf(fmaxf(a2[1], 0.f)) << 16);
            p.y = (unsigned)f2bf(fmaxf(a2[2], 0.f)) | ((unsigned)f2bf(fmaxf(a2[3], 0.f)) << 16);
            *(uint2*)(tp2 + ((size_t)j << 6) + TB + grp * 4) = p;
        }
    } else if (b < PRE_NFC + PRE_TG + PRE_W2C){
        int bb = b - PRE_NFC - PRE_TG;
        int k = bb & 63;
        const float* srcw = ((bb < 64) ? e1w2 : e2w2) + (size_t)k * 4096;
        unsigned short* dstw = (bb < 64) ? w2t1 : w2t2;
        for (int idx = tid; idx < 4096; idx += 256) tile[idx >> 6][idx & 63] = srcw[idx];
        __syncthreads();
        for (int idx = tid; idx < 4096; idx += 256){
            int o = idx >> 6, i = idx & 63;
            dstw[((size_t)(k * 64 + o) << 6) + i] = f2bf(tile[i][o]);
        }
    } else {
        int e = (b - PRE_NFC - PRE_TG - PRE_W2C) * 256 + tid;
        if (e < N_EDGES) atomicAdd(&counts[src[e]], 1);
    }
}

// scan rowptr from counts (plain loads — kernel boundary gives coherence); zero cursor
__global__ void csr_scan_kernel(const int* __restrict__ counts, int* __restrict__ rowptr,
                                int* __restrict__ cursor){
    __shared__ int part[256];
    int tid = threadIdx.x;
    const int CH = (N_NODES + 255) / 256;      // 40
    int base = tid * CH, s = 0;
    for (int i = 0; i < CH; ++i){ int idx = base + i; if (idx < N_NODES){ cursor[idx] = 0; s += counts[idx]; } }
    part[tid] = s; __syncthreads();
    for (int off = 1; off < 256; off <<= 1){
        int v = (tid >= off) ? part[tid - off] : 0;
        __syncthreads();
        part[tid] += v;
        __syncthreads();
    }
    int run = part[tid] - s;
    for (int i = 0; i < CH; ++i){ int idx = base + i; if (idx < N_NODES){ rowptr[idx] = run; run += counts[idx]; } }
    if (tid == 255) rowptr[N_NODES] = run;
}

// ---------------- per-layer: hb2(MFMA)+agg0 | gmat (MFMA -> fp8 G) | scatter ---------------
#define NBH2 157
#define NBG  (157 * 8)
template<int SCAT>
__global__ void __launch_bounds__(256) layerA_kernel(
        const float* __restrict__ hx, const unsigned short* __restrict__ b2t,
        float* __restrict__ hb2, float* __restrict__ agg,
        const unsigned short* __restrict__ w2t, unsigned char* __restrict__ G,
        const int* __restrict__ src, const int* __restrict__ dst,
        const int* __restrict__ rowptr, int* __restrict__ cursor,
        int* __restrict__ eidx, int* __restrict__ dsts){
    __shared__ unsigned stgu[8192];            // 32 KB (gmat branch only)
    int b = blockIdx.x, tid = threadIdx.x;
    int wid = tid >> 6, l = tid & 63;
    int m16 = l & 15, grp = l >> 4;

    if (b < NBH2){
        int node = b * 64 + wid * 16 + m16;
        short8 h0 = {0,0,0,0,0,0,0,0}, h1 = {0,0,0,0,0,0,0,0};
        if (node < N_NODES){
            const float* hp = hx + ((size_t)node << 6) + grp * 8;
            h0 = pack_bf8(*(const float4*)hp, *(const float4*)(hp + 4));
            h1 = pack_bf8(*(const float4*)(hp + 32), *(const float4*)(hp + 36));
        }
        #pragma unroll
        for (int TB = 0; TB < 64; TB += 16){
            short8 c0 = *(const short8*)(b2t + (TB + m16) * 64 + grp * 8);
            short8 c1 = *(const short8*)(b2t + (TB + m16) * 64 + 32 + grp * 8);
            f32x4 acc = {0.f, 0.f, 0.f, 0.f};
            acc = __builtin_amdgcn_mfma_f32_16x16x32_bf16(c0, h0, acc, 0, 0, 0);
            acc = __builtin_amdgcn_mfma_f32_16x16x32_bf16(c1, h1, acc, 0, 0, 0);
            if (node < N_NODES) *(f32x4*)(hb2 + ((size_t)node << 6) + TB + grp * 4) = acc;
        }
        f32x4 z = {0.f, 0.f, 0.f, 0.f};
        #pragma unroll
        for (int q = 0; q < 4; ++q){
            int chunk = q * 256 + tid;
            int n = b * 64 + (chunk >> 4), c = (chunk & 15) * 4;
            if (n < N_NODES) *(f32x4*)(agg + ((size_t)n << 6) + c) = z;
        }
    } else if (b < NBH2 + NBG){
        int g = b - NBH2;
        int bx = g >> 3, by = g & 7;
        int n0 = bx * 64;
        int cb = by * 512;

        short8 bf0[4], bf1[4];
        #pragma unroll
        for (int ng = 0; ng < 4; ++ng){
            int node = n0 + ng * 16 + m16;
            short8 b0 = {0,0,0,0,0,0,0,0}, b1v = {0,0,0,0,0,0,0,0};
            if (node < N_NODES){
                const float* hp = hx + ((size_t)node << 6) + grp * 8;
                b0  = pack_bf8(*(const float4*)hp, *(const float4*)(hp + 4));
                b1v = pack_bf8(*(const float4*)(hp + 32), *(const float4*)(hp + 36));
            }
            bf0[ng] = b0; bf1[ng] = b1v;
        }

        #pragma unroll
        for (int t = 0; t < 8; ++t){
            int TB = cb + t * 64 + wid * 16;
            const unsigned short* ap = w2t + ((size_t)(TB + m16) << 6) + grp * 8;
            short8 a0 = *(const short8*)ap;
            short8 a1 = *(const short8*)(ap + 32);
            int colLocal = t * 64 + wid * 16 + grp * 4;
            #pragma unroll
            for (int ng = 0; ng < 4; ++ng){
                f32x4 acc = {0.f, 0.f, 0.f, 0.f};
                acc = __builtin_amdgcn_mfma_f32_16x16x32_bf16(a0, bf0[ng], acc, 0, 0, 0);
                acc = __builtin_amdgcn_mfma_f32_16x16x32_bf16(a1, bf1[ng], acc, 0, 0, 0);
                int pk = __builtin_amdgcn_cvt_pk_fp8_f32(acc[0], acc[1], 0, false);
                pk = __builtin_amdgcn_cvt_pk_fp8_f32(acc[2], acc[3], pk, true);
                int row = ng * 16 + m16;
                int dw = ((row << 7) + (colLocal >> 2)) ^ ((row & 7) << 2);
                stgu[dw] = (unsigned)pk;
            }
        }
        __syncthreads();
        #pragma unroll
        for (int s2 = 0; s2 < 8; ++s2){
            int ci = s2 * 256 + tid;
            int row = ci >> 5;
            int c = ci & 31;
            int node = n0 + row;
            int dwb = ((row << 7) + (c << 2)) ^ ((row & 7) << 2);
            uint4 v = *(const uint4*)&stgu[dwb];
            if (node < N_NODES)
                *(uint4*)(G + (size_t)node * 4096 + cb + c * 16) = v;
        }
    } else if (SCAT){
        int e = (b - NBH2 - NBG) * 256 + tid;
        if (e < N_EDGES){
            int s = src[e];
            int j = rowptr[s] + atomicAdd(&cursor[s], 1);
            eidx[j] = e; dsts[j] = dst[e];
        }
    }
}

// ---------------- msg: 1 wave per node (fine-grained load balance); coalesced G row -------
__global__ void __launch_bounds__(64) msg_csr_kernel(
        const unsigned short* __restrict__ tp, const unsigned char* __restrict__ G,
        const float* __restrict__ hb2, const int* __restrict__ rowptr,
        const int* __restrict__ eidx, const int* __restrict__ dsts,
        float* __restrict__ agg){
    int s = blockIdx.x;
    int o = threadIdx.x;
    __shared__ unsigned char gl[4096] __attribute__((aligned(16)));
    __shared__ unsigned short ts[64] __attribute__((aligned(16)));
    int r0 = rowptr[s], r1 = rowptr[s + 1];
    if (r0 == r1) return;
    const uint4* gs = (const uint4*)(G + (size_t)s * 4096);
    uint4* gld = (uint4*)gl;
    #pragma unroll
    for (int i = 0; i < 4; ++i) gld[i * 64 + o] = gs[i * 64 + o];   // 4 KB coalesced
    float g[64];
    #pragma unroll
    for (int k = 0; k < 64; k += 2){
        unsigned b0 = gl[(k << 6) + o];
        unsigned b1 = gl[((k + 1) << 6) + o];
        f32x2 d = __builtin_amdgcn_cvt_pk_f32_fp8((int)(b0 | (b1 << 8)), false);
        g[k] = d[0]; g[k + 1] = d[1];
    }
    float hb = hb2[((size_t)s << 6) + o];
    for (int j = r0; j < r1; ++j){
        int e = eidx[j];
        ts[o] = tp[((size_t)e << 6) + o];
        float acc = hb;
        #pragma unroll
        for (int k8 = 0; k8 < 8; ++k8){
            short8 tv = *(const short8*)&ts[k8 * 8];
            #pragma unroll
            for (int u = 0; u < 8; ++u) acc += bf2f((unsigned short)tv[u]) * g[k8 * 8 + u];
        }
        atomicAdd(&agg[((size_t)dsts[j] << 6) + o], acc);
    }
}

// ---------------- combine (MFMA root GEMM); L2: LDS-staged conflict-free pooling ----------
template<int L2>
__global__ void __launch_bounds__(256) combine_kernel(
        const float* __restrict__ agg, const float* __restrict__ hx,
        const unsigned short* __restrict__ rootT, const float* __restrict__ bias,
        float* __restrict__ outp, const int* __restrict__ batch, float* __restrict__ hg){
    __shared__ float otile[64][65];
    int b = blockIdx.x, tid = threadIdx.x;
    int wid = tid >> 6, l = tid & 63;
    int m16 = l & 15, grp = l >> 4;
    int node = b * 64 + wid * 16 + m16;
    int lnode = wid * 16 + m16;
    bool ok = node < N_NODES;
    short8 h0 = {0,0,0,0,0,0,0,0}, h1 = {0,0,0,0,0,0,0,0};
    if (ok){
        const float* hp = hx + ((size_t)node << 6) + grp * 8;
        h0 = pack_bf8(*(const float4*)hp, *(const float4*)(hp + 4));
        h1 = pack_bf8(*(const float4*)(hp + 32), *(const float4*)(hp + 36));
    }
    #pragma unroll
    for (int TB = 0; TB < 64; TB += 16){
        short8 c0 = *(const short8*)(rootT + (TB + m16) * 64 + grp * 8);
        short8 c1 = *(const short8*)(rootT + (TB + m16) * 64 + 32 + grp * 8);
        f32x4 acc;
        if (ok){
            f32x4 av = *(const f32x4*)(agg + ((size_t)node << 6) + TB + grp * 4);
            f32x4 bv = *(const f32x4*)(bias + TB + grp * 4);
            acc[0] = av[0] + bv[0]; acc[1] = av[1] + bv[1];
            acc[2] = av[2] + bv[2]; acc[3] = av[3] + bv[3];
        } else {
            acc[0] = acc[1] = acc[2] = acc[3] = 0.f;
        }
        acc = __builtin_amdgcn_mfma_f32_16x16x32_bf16(c0, h0, acc, 0, 0, 0);
        acc = __builtin_amdgcn_mfma_f32_16x16x32_bf16(c1, h1, acc, 0, 0, 0);
        if (L2){
            #pragma unroll
            for (int r = 0; r < 4; ++r) otile[lnode][TB + grp * 4 + r] = lrelu(acc[r]);
        } else if (ok){
            f32x4 rv;
            rv[0] = lrelu(acc[0]); rv[1] = lrelu(acc[1]);
            rv[2] = lrelu(acc[2]); rv[3] = lrelu(acc[3]);
            *(f32x4*)(outp + ((size_t)node << 6) + TB + grp * 4) = rv;
        }
    }
    if (L2){
        __syncthreads();
        #pragma unroll
        for (int p = 0; p < 16; ++p){
            int ln = wid * 16 + p;
            int n = b * 64 + ln;
            if (n < N_NODES)
                atomicAdd(&hg[batch[n] * 64 + l], otile[ln][l]);
        }
    }
}

__global__ void head_kernel(const float* __restrict__ hg, const float* __restrict__ fc1w,
                            const float* __restrict__ fc1b, const float* __restrict__ fc2w,
                            const float* __restrict__ fc2b, float* __restrict__ out){
    int g = threadIdx.x;
    const float* row = hg + g * 64;
    float h1[32];
    #pragma unroll
    for (int j = 0; j < 32; ++j){
        float a = fc1b[j];
        #pragma unroll 8
        for (int i = 0; i < 64; ++i) a += row[i] * fc1w[i * 32 + j];
        h1[j] = lrelu(a);
    }
    float o = fc2b[0];
    #pragma unroll
    for (int j = 0; j < 32; ++j) o += h1[j] * fc2w[j];
    out[g] = o;
}

extern "C" void kernel_launch(void* const* d_in, const int* in_sizes, int n_in,
                              void* d_out, int out_size, void* d_ws, size_t ws_size,
                              hipStream_t stream){
    const float* x      = (const float*)d_in[0];
    const int*   ei     = (const int*)  d_in[1];
    const float* ea     = (const float*)d_in[2];
    const int*   batch  = (const int*)  d_in[3];
    const float* nfc_w  = (const float*)d_in[4];
    const float* nfc_b  = (const float*)d_in[5];
    const float* e1w1   = (const float*)d_in[6];
    const float* e1b1   = (const float*)d_in[7];
    const float* e1w2   = (const float*)d_in[8];
    const float* e1b2   = (const float*)d_in[9];
    const float* g1root = (const float*)d_in[10];
    const float* g1bias = (const float*)d_in[11];
    const float* e2w1   = (const float*)d_in[12];
    const float* e2b1   = (const float*)d_in[13];
    const float* e2w2   = (const float*)d_in[14];
    const float* e2b2   = (const float*)d_in[15];
    const float* g2root = (const float*)d_in[16];
    const float* g2bias = (const float*)d_in[17];
    const float* fc1w   = (const float*)d_in[18];
    const float* fc1b   = (const float*)d_in[19];
    const float* fc2w   = (const float*)d_in[20];
    const float* fc2b   = (const float*)d_in[21];
    float* out = (float*)d_out;

    const int* src = ei;
    const int* dst = ei + N_EDGES;

    // workspace carve-up
    char* ws = (char*)d_ws;
    float* hx1 = (float*)ws;               ws += (size_t)N_NODES * 64 * 4;
    float* hx2 = (float*)ws;               ws += (size_t)N_NODES * 64 * 4;
    unsigned short* tp1 = (unsigned short*)ws; ws += (size_t)N_EDGES * 64 * 2;
    unsigned short* tp2 = (unsigned short*)ws; ws += (size_t)N_EDGES * 64 * 2;
    float* hb2 = (float*)ws;               ws += (size_t)N_NODES * 64 * 4;
    float* agg = (float*)ws;               ws += (size_t)N_NODES * 64 * 4;
    float* hg  = (float*)ws;               ws += (size_t)N_GRAPHS * 64 * 4;
    unsigned short* w2t1 = (unsigned short*)ws; ws += (size_t)64 * 64 * 64 * 2;
    unsigned short* w2t2 = (unsigned short*)ws; ws += (size_t)64 * 64 * 64 * 2;
    unsigned short* nfc_wt = (unsigned short*)ws; ws += (size_t)8192 * 2;
    unsigned short* w1t1 = (unsigned short*)ws; ws += (size_t)2048 * 2;
    unsigned short* w1t2 = (unsigned short*)ws; ws += (size_t)2048 * 2;
    unsigned short* b2t1 = (unsigned short*)ws; ws += (size_t)4096 * 2;
    unsigned short* b2t2 = (unsigned short*)ws; ws += (size_t)4096 * 2;
    unsigned short* rootT1 = (unsigned short*)ws; ws += (size_t)4096 * 2;
    unsigned short* rootT2 = (unsigned short*)ws; ws += (size_t)4096 * 2;
    int* counts = (int*)ws;                ws += (size_t)10240 * 4;
    int* cursor = (int*)ws;                ws += (size_t)10240 * 4;
    int* rowptr = (int*)ws;                ws += (size_t)10240 * 4;
    int* eidx   = (int*)ws;                ws += (size_t)N_EDGES * 4;
    int* dsts   = (int*)ws;                ws += (size_t)N_EDGES * 4;
    unsigned char* G = (unsigned char*)ws;  // 41 MB fp8

    // 1: init; 2: pre; 3: scan
    init_kernel<<<47, 256, 0, stream>>>(counts, hg, nfc_w, nfc_wt,
        e1w1, w1t1, e2w1, w1t2, e1b2, b2t1, e2b2, b2t2, g1root, rootT1, g2root, rootT2);
    pre_kernel<<<PRE_NFC + PRE_TG + PRE_W2C + PRE_CNT, 256, 0, stream>>>(
        x, nfc_wt, nfc_b, hx1, ea, w1t1, e1b1, tp1, w1t2, e2b1, tp2,
        e1w2, w2t1, e2w2, w2t2, src, counts);
    csr_scan_kernel<<<1, 256, 0, stream>>>(counts, rowptr, cursor);

    // ---------- layer 1 (4,5,6) — scatter folded into layerA as extra parallel blocks ------
    layerA_kernel<1><<<NBH2 + NBG + 250, 256, 0, stream>>>(
        hx1, b2t1, hb2, agg, w2t1, G, src, dst, rowptr, cursor, eidx, dsts);
    msg_csr_kernel<<<N_NODES, 64, 0, stream>>>(tp1, G, hb2, rowptr, eidx, dsts, agg);
    combine_kernel<0><<<157, 256, 0, stream>>>(agg, hx1, rootT1, g1bias, hx2, batch, nullptr);

    // ---------- layer 2 (7,8,9) ----------
    layerA_kernel<0><<<NBH2 + NBG, 256, 0, stream>>>(
        hx2, b2t2, hb2, agg, w2t2, G, src, dst, rowptr, cursor, eidx, dsts);
    msg_csr_kernel<<<N_NODES, 64, 0, stream>>>(tp2, G, hb2, rowptr, eidx, dsts, agg);
    combine_kernel<1><<<157, 256, 0, stream>>>(agg, hx2, rootT2, g2bias, nullptr, batch, hg);

    // 10: head
    head_kernel<<<1, 64, 0, stream>>>(hg, fc1w, fc1b, fc2w, fc2b, out);
}